// Round 3
// baseline (18711.385 us; speedup 1.0000x reference)
//
#include <hip/hip_runtime.h>
#include <math.h>

#define T_STEPS 4096
#define RES     2048
#define NF      8
#define NR      8
#define K_WG    256      // 256 WGs (1/CU) x 4 waves; WG owns 8 cols, wave owns 2
#define NTHR    256
#define SENTINEL 2.0f    // reachable |x| < 1 strictly (|x|<=0.7|x|+0.3); 2.0 unreachable

// ---------------------------------------------------------------------------
// drive[t][j] = Win[0][j] + sum_f inp[t][f] * Win[1+f][j]
__global__ void k_drive(const float* __restrict__ inp, const float* __restrict__ Win,
                        float* __restrict__ drive) {
    int idx = blockIdx.x * blockDim.x + threadIdx.x;   // [0, T*RES)
    int t = idx >> 11;
    int j = idx & (RES - 1);
    float d = Win[j];
#pragma unroll
    for (int f = 0; f < NF; ++f)
        d += inp[t * NF + f] * Win[(1 + f) * RES + j];
    drive[idx] = d;
}

// ---------------------------------------------------------------------------
// X[0][:] = 0 (valid initial state); X[1..T][:] = SENTINEL (unwritten)
__global__ void k_init(float* __restrict__ X) {
    int tid = threadIdx.x + blockIdx.x * blockDim.x;
    int stride = blockDim.x * gridDim.x;
    const int total = (T_STEPS + 1) * RES;
    for (int i = tid; i < total; i += stride)
        X[i] = (i < RES) ? 0.f : SENTINEL;
}

// ---------------------------------------------------------------------------
// Persistent dataflow recurrence.
//  - WG k owns output columns [8k, 8k+8); wave w owns cols 8k+2w, 8k+2w+1.
//  - W fragment: 64 floats/lane (32 rows x 2 cols) -> ~120 VGPR total, no spill
//    (round-2 failure: 128-float fragment forced scratch spills, VGPR=112).
//  - Sync: sentinel-in-data. Only wave 0 polls global row t (agent-scope
//    relaxed atomic loads, predicated re-poll), stages it into LDS
//    (double-buffered), releases LDS flag = t+1. Waves 1-3 poll the LDS flag.
//    Safety of 2-buffer: wave0 can only stage row t+2 after the whole grid
//    published row t+2, which requires its siblings to have consumed buffer
//    (t&1) at step t already.
__global__ __launch_bounds__(NTHR, 1) void k_recur(
        const float* __restrict__ W, const float* __restrict__ drive,
        float* __restrict__ X) {
    __shared__ float    xs[2][RES];
    __shared__ unsigned flag;        // monotonic: last staged step+1

    const int tid  = threadIdx.x;
    const int wave = tid >> 6;
    const int lane = tid & 63;
    const int c0   = blockIdx.x * 8 + wave * 2;   // this wave's 2 output cols

    // W fragment: Wr[i] = W[i*64+lane][c0], W[i*64+lane][c0+1]
    float2 Wr[32];
#pragma unroll
    for (int i = 0; i < 32; ++i)
        Wr[i] = *reinterpret_cast<const float2*>(&W[(size_t)(i * 64 + lane) * RES + c0]);

    if (tid == 0) flag = 0;
    __syncthreads();   // only barrier in the kernel (one-time init)

    float xprev = 0.f;   // lanes 0-1: own column's x_t (x_0 = 0)
    float xv[32];

    for (int t = 0; t < T_STEPS; ++t) {
        // Independent of x_t: prefetch drive for this wave's columns.
        float dr = (lane < 2) ? drive[(size_t)t * RES + c0 + lane] : 0.f;

        if (wave == 0) {
            const float* xrow = X + (size_t)t * RES;
            // First sweep: load everything.
#pragma unroll
            for (int i = 0; i < 32; ++i)
                xv[i] = __hip_atomic_load(&xrow[i * 64 + lane],
                                          __ATOMIC_RELAXED, __HIP_MEMORY_SCOPE_AGENT);
            for (;;) {
                float m = 0.f;
#pragma unroll
                for (int i = 0; i < 32; ++i)
                    m = fmaxf(m, __builtin_fabsf(xv[i]));
                if (__all(m < 1.5f)) break;
                __builtin_amdgcn_s_sleep(1);
                // Re-poll only still-sentinel elements (exec-masked loads).
#pragma unroll
                for (int i = 0; i < 32; ++i)
                    if (__builtin_fabsf(xv[i]) > 1.5f)
                        xv[i] = __hip_atomic_load(&xrow[i * 64 + lane],
                                                  __ATOMIC_RELAXED,
                                                  __HIP_MEMORY_SCOPE_AGENT);
            }
            // Stage into LDS (stride-64 layout: conflict-free, 2 lanes/bank).
            float* dst = xs[t & 1];
#pragma unroll
            for (int i = 0; i < 32; ++i)
                dst[i * 64 + lane] = xv[i];
            // Release: compiler drains lgkmcnt (whole wave's ds_writes) first.
            if (lane == 0)
                __hip_atomic_store(&flag, (unsigned)(t + 1),
                                   __ATOMIC_RELEASE, __HIP_MEMORY_SCOPE_WORKGROUP);
        } else {
            while (__hip_atomic_load(&flag, __ATOMIC_ACQUIRE,
                                     __HIP_MEMORY_SCOPE_WORKGROUP) < (unsigned)(t + 1))
                __builtin_amdgcn_s_sleep(1);
            const float* src = xs[t & 1];
#pragma unroll
            for (int i = 0; i < 32; ++i)
                xv[i] = src[i * 64 + lane];
        }

        // z[c0+j] partial sums: 64 FMAs/lane.
        float a0 = 0.f, a1 = 0.f;
#pragma unroll
        for (int i = 0; i < 32; ++i) {
            a0 = fmaf(xv[i], Wr[i].x, a0);
            a1 = fmaf(xv[i], Wr[i].y, a1);
        }
        // 64-lane butterfly: all lanes end with both column sums.
#pragma unroll
        for (int off = 32; off >= 1; off >>= 1) {
            a0 += __shfl_xor(a0, off, 64);
            a1 += __shfl_xor(a1, off, 64);
        }

        if (lane < 2) {
            float a  = lane ? a1 : a0;
            float xn = 0.7f * xprev + 0.3f * tanhf(dr + a);
            xprev = xn;   // own column: no reload next step
            __hip_atomic_store(&X[(size_t)(t + 1) * RES + c0 + lane], xn,
                               __ATOMIC_RELAXED, __HIP_MEMORY_SCOPE_AGENT);
        }
    }
}

// ---------------------------------------------------------------------------
// Y[t][r] = Wout[0][r] + sum_f inp[t][f]*Wout[1+f][r] + sum_j X[t+1][j]*Wout[9+j][r]
__global__ void k_readout(const float* __restrict__ inp, const float* __restrict__ Wout,
                          const float* __restrict__ X, float* __restrict__ Y) {
    int t   = blockIdx.x;
    int tid = threadIdx.x;
    int r   = tid & (NR - 1);
    int gph = tid >> 3;                    // 32 groups
    const float* x = X + (size_t)(t + 1) * RES;
    float p = 0.f;
#pragma unroll 4
    for (int m = 0; m < RES / 32; ++m) {
        int j = gph * (RES / 32) + m;
        p += x[j] * Wout[(size_t)(1 + NF + j) * NR + r];
    }
    __shared__ float red[NTHR];
    red[tid] = p;
    __syncthreads();
    for (int s = NTHR / 2; s >= NR; s >>= 1) {
        if (tid < s) red[tid] += red[tid + s];
        __syncthreads();
    }
    if (tid < NR) {
        float y = Wout[tid];
#pragma unroll
        for (int f = 0; f < NF; ++f)
            y += inp[t * NF + f] * Wout[(1 + f) * NR + tid];
        Y[t * NR + tid] = y + red[tid];
    }
}

// ---------------------------------------------------------------------------
extern "C" void kernel_launch(void* const* d_in, const int* in_sizes, int n_in,
                              void* d_out, int out_size, void* d_ws, size_t ws_size,
                              hipStream_t stream) {
    const float* inp  = (const float*)d_in[0];   // (T, 8)
    const float* Win  = (const float*)d_in[1];   // (9, 2048)
    const float* W    = (const float*)d_in[2];   // (2048, 2048)
    const float* Wout = (const float*)d_in[3];   // (2057, 8)
    float* Y = (float*)d_out;                    // (T, 8)

    float* drive = (float*)d_ws;                            // 32 MB
    float* X     = drive + (size_t)T_STEPS * RES;           // 32 MB + 8 KB

    k_init<<<2048, NTHR, 0, stream>>>(X);
    k_drive<<<(T_STEPS * RES) / NTHR, NTHR, 0, stream>>>(inp, Win, drive);
    k_recur<<<K_WG, NTHR, 0, stream>>>(W, drive, X);
    k_readout<<<T_STEPS, NTHR, 0, stream>>>(inp, Wout, X, Y);
}